// Round 1
// baseline (260.645 us; speedup 1.0000x reference)
//
#include <hip/hip_runtime.h>

typedef unsigned short u16;
typedef unsigned int u32;
typedef float f32x4 __attribute__((ext_vector_type(4)));
typedef short bf16x8 __attribute__((ext_vector_type(8)));

#define NB 8
#define FH 37
#define FW 50
#define FHW 1850
#define MTOT 14800
#define CIN 512
#define KTOT 4608
#define HP 39
#define WP 52
#define ANCH 16650
#define NG 20

// ---------- helpers ----------
__device__ __forceinline__ u16 f2bf(float f) {
    u32 u = __float_as_uint(f);
    u += 0x7fffu + ((u >> 16) & 1u);   // round-to-nearest-even
    return (u16)(u >> 16);
}

__device__ __forceinline__ void gl2lds16(const u16* g, u16* l) {
    __builtin_amdgcn_global_load_lds((const __attribute__((address_space(1))) void*)(g),
                                     (__attribute__((address_space(3))) void*)(l),
                                     16, 0, 0);
}

__device__ __forceinline__ void anchor_box(int a, float& x1, float& y1, float& x2, float& y2) {
    // a = ((x*37 + y)*3 + si)*3 + bi
    int x = a / 333;
    int rem = a - x * 333;
    int y = rem / 9;
    int r2 = rem - y * 9;
    int si = r2 / 3;
    int bi = r2 - si * 3;
    float s = (float)(8 << si);
    float fx = (float)x, fy = (float)y;
    float ax1, ay1, ax2, ay2;
    if (bi == 0)      { float h = s * 0.5f;  ax1 = fx - h; ay1 = fy - h; ax2 = fx + h; ay2 = fy + h; }
    else if (bi == 1) { float q = s * 0.25f; ax1 = fx - s; ay1 = fy - q; ax2 = fx + s; ay2 = fy + q; }
    else              { float q = s * 0.25f; ax1 = fx - q; ay1 = fy - s; ax2 = fx + q; ay2 = fy + s; }
    x1 = ax1 * 16.f; y1 = ay1 * 16.f; x2 = ax2 * 16.f; y2 = ay2 * 16.f;
}

// ---------- prep kernels ----------
__global__ void k_zero(uint4* __restrict__ p) {
    int i = blockIdx.x * 256 + threadIdx.x;   // exactly 1038336 launched
    p[i] = make_uint4(0u, 0u, 0u, 0u);
}

// feats (B,512,37,50) f32  ->  apad (B,39,52,512) bf16, interior only
__global__ void k_transpose(const float* __restrict__ feats, u16* __restrict__ apad) {
    __shared__ float tile[32][33];
    int b  = blockIdx.z;
    int hw0 = blockIdx.x * 32;
    int c0  = blockIdx.y * 32;
    int tx = threadIdx.x, ty = threadIdx.y;
    int hw = hw0 + tx;
    if (hw < FHW) tile[ty][tx] = feats[(b * 512 + c0 + ty) * FHW + hw];
    __syncthreads();
    int hw2 = hw0 + ty;
    if (hw2 < FHW) {
        int h = hw2 / FW, w = hw2 - h * FW;
        apad[(((b * HP) + h + 1) * WP + (w + 1)) * 512 + c0 + tx] = f2bf(tile[tx][ty]);
    }
}

// w3 (512,512,3,3) f32 -> wt[n][tap*512+ci] bf16 (K-contiguous rows, B^T form)
__global__ void k_wt(const float* __restrict__ w3, u16* __restrict__ wt) {
    int i = blockIdx.x * 256 + threadIdx.x;   // exactly 2359296 launched
    int n = i / KTOT;
    int k = i - n * KTOT;
    int tap = k >> 9;
    int ci  = k & 511;
    wt[i] = f2bf(w3[n * KTOT + ci * 9 + tap]);
}

// head weights -> whd[n][ci] bf16, n in [0,64): 0..17 = wc, 18..53 = wb, rest 0
__global__ void k_whd(const float* __restrict__ wc, const float* __restrict__ wb,
                      u16* __restrict__ whd) {
    int i = blockIdx.x * 256 + threadIdx.x;   // exactly 32768 launched
    int n = i >> 9;
    int ci = i & 511;
    float v = 0.f;
    if (n < 18) v = wc[n * 512 + ci];
    else if (n < 54) v = wb[(n - 18) * 512 + ci];
    whd[i] = f2bf(v);
}

// ---------- 3x3 conv as implicit GEMM (m97 structure) ----------
// C[m][n] = sum_k A[m][k] * Bt[n][k],  M=14800, N=512, K=4608
__global__ __launch_bounds__(256) void k_conv(const u16* __restrict__ apad,
                                              const u16* __restrict__ wt,
                                              const float* __restrict__ b3,
                                              u16* __restrict__ act) {
    __shared__ u16 As[128 * 32];   // [m][k], k contiguous
    __shared__ u16 Bs[128 * 32];   // [n][k], k contiguous
    int tid = threadIdx.x;
    int wave = tid >> 6, lane = tid & 63;
    int m0 = blockIdx.x * 128;
    int n0 = blockIdx.y * 128;
    int wr = wave >> 1, wn = wave & 1;
    int lm = lane & 15, lq = lane >> 4;

    f32x4 acc[4][4] = {};

    int koff = (tid & 3) * 8;
    int aBase[2], bRow[2];
    for (int i = 0; i < 2; i++) {
        int r = i * 64 + (tid >> 2);
        int m = m0 + r; if (m > MTOT - 1) m = MTOT - 1;
        int b = m / FHW; int hw = m - b * FHW;
        int h = hw / FW; int w = hw - h * FW;
        aBase[i] = ((b * HP + h) * WP + w) * 512 + koff;
        bRow[i]  = (n0 + r) * KTOT + koff;
    }
    u16* aLds[2]; u16* bLds[2];
    for (int i = 0; i < 2; i++) {
        aLds[i] = &As[(i * 256 + wave * 64) * 8];
        bLds[i] = &Bs[(i * 256 + wave * 64) * 8];
    }

    for (int kk = 0; kk < KTOT; kk += 32) {
        int tap = kk >> 9;
        int ci0 = kk & 511;
        int dy = tap / 3; int dx = tap - dy * 3;
        int aOfs = (dy * WP + dx) * 512 + ci0;
        gl2lds16(apad + aBase[0] + aOfs, aLds[0]);
        gl2lds16(apad + aBase[1] + aOfs, aLds[1]);
        gl2lds16(wt + bRow[0] + kk, bLds[0]);
        gl2lds16(wt + bRow[1] + kk, bLds[1]);
        __syncthreads();
        bf16x8 a[4], b[4];
        for (int i = 0; i < 4; i++)
            a[i] = *(const bf16x8*)&As[(wr * 64 + i * 16 + lm) * 32 + lq * 8];
        for (int j = 0; j < 4; j++)
            b[j] = *(const bf16x8*)&Bs[(wn * 64 + j * 16 + lm) * 32 + lq * 8];
        for (int i = 0; i < 4; i++)
            for (int j = 0; j < 4; j++)
                acc[i][j] = __builtin_amdgcn_mfma_f32_16x16x32_bf16(a[i], b[j], acc[i][j], 0, 0, 0);
        __syncthreads();
    }

    for (int j = 0; j < 4; j++) {
        int n = n0 + wn * 64 + j * 16 + lm;
        float bias = b3[n];
        for (int i = 0; i < 4; i++) {
            int mb = m0 + wr * 64 + i * 16 + lq * 4;
            for (int r = 0; r < 4; r++) {
                int m = mb + r;
                if (m < MTOT) {
                    float v = acc[i][j][r] + bias;
                    act[m * 512 + n] = f2bf(v > 0.f ? v : 0.f);
                }
            }
        }
    }
}

// ---------- 1x1 head convs: S[m][n] = sum_k act[m][k]*whd[n][k], N=64 padded ----------
__global__ __launch_bounds__(256) void k_heads(const u16* __restrict__ act,
                                               const u16* __restrict__ whd,
                                               float* __restrict__ S) {
    int tid = threadIdx.x;
    int wave = tid >> 6, lane = tid & 63;
    int lm = lane & 15, lq = lane >> 4;
    int m0 = blockIdx.x * 128 + wave * 32;
    f32x4 acc[2][4] = {};
    int mrow[2];
    for (int i = 0; i < 2; i++) {
        int m = m0 + i * 16 + lm;
        if (m > MTOT - 1) m = MTOT - 1;
        mrow[i] = m * 512;
    }
    for (int kk = 0; kk < 512; kk += 32) {
        bf16x8 a[2], b[4];
        for (int i = 0; i < 2; i++)
            a[i] = *(const bf16x8*)&act[mrow[i] + kk + lq * 8];
        for (int j = 0; j < 4; j++)
            b[j] = *(const bf16x8*)&whd[(j * 16 + lm) * 512 + kk + lq * 8];
        for (int i = 0; i < 2; i++)
            for (int j = 0; j < 4; j++)
                acc[i][j] = __builtin_amdgcn_mfma_f32_16x16x32_bf16(a[i], b[j], acc[i][j], 0, 0, 0);
    }
    for (int i = 0; i < 2; i++) {
        for (int r = 0; r < 4; r++) {
            int m = m0 + i * 16 + lq * 4 + r;
            if (m < MTOT) {
                for (int j = 0; j < 4; j++)
                    S[m * 64 + j * 16 + lm] = acc[i][j][r];
            }
        }
    }
}

// ---------- softmax pairs + bbox concat ----------
__global__ void k_final(const float* __restrict__ S, const float* __restrict__ bc,
                        const float* __restrict__ bb, float* __restrict__ out) {
    int m = blockIdx.x * 256 + threadIdx.x;
    if (m >= MTOT) return;
    int b = m / FHW;
    int hw = m - b * FHW;
    float* ob = out + b * 54 * FHW + hw;
    const float* s = S + m * 64;
    for (int c = 0; c < 9; c++) {
        float s0 = s[c] + bc[c];
        float s1 = s[c + 9] + bc[c + 9];
        float mxv = fmaxf(s0, s1);
        float e0 = __expf(s0 - mxv), e1 = __expf(s1 - mxv);
        float inv = 1.f / (e0 + e1);
        ob[c * FHW] = e0 * inv;
        ob[(c + 9) * FHW] = e1 * inv;
    }
    for (int j = 0; j < 36; j++)
        ob[(18 + j) * FHW] = s[18 + j] + bb[j];
}

// ---------- idx[b] = argmax_g iou(anchor19, gt[b][g]) (inside-masked, first-max) ----------
__global__ void k_idx(const float* __restrict__ gt, const float* __restrict__ im,
                      int* __restrict__ idxb) {
    int b = threadIdx.x;
    if (b >= NB) return;
    float x1, y1, x2, y2;
    anchor_box(19, x1, y1, x2, y2);
    bool inside = (x1 >= 0.f) && (y1 >= 0.f) && (x2 < im[1]) && (y2 < im[0]);
    float aa = (x2 - x1) * (y2 - y1);
    float best = -1.f; int bg = 0;
    for (int g = 0; g < NG; g++) {
        const float* gb = gt + (b * NG + g) * 4;
        float l = fmaxf(x1, gb[0]), r = fminf(x2, gb[2]);
        float t = fmaxf(y1, gb[1]), bo = fminf(y2, gb[3]);
        float v = 0.f;
        if (l < r && t < bo) {
            float inter = (r - l) * (bo - t);
            float ag = (gb[2] - gb[0]) * (gb[3] - gb[1]);
            v = inter / (aa + ag - inter);
        }
        if (!inside) v = 0.f;
        if (v > best) { best = v; bg = g; }
    }
    idxb[b] = bg;
}

// ---------- IoU matrix + labels ----------
__global__ __launch_bounds__(256) void k_iou(const float* __restrict__ gt, const float* __restrict__ im,
                                             const int* __restrict__ idxb,
                                             float* __restrict__ iou_out, float* __restrict__ lab) {
    __shared__ float g4[NG * 4];
    __shared__ float imv[2];
    __shared__ int idxs;
    int t = threadIdx.x;
    int b = blockIdx.y;
    if (t < NG * 4) g4[t] = gt[b * NG * 4 + t];
    if (t < 2) imv[t] = im[t];
    if (t == 0) idxs = idxb[b];
    __syncthreads();
    int a = blockIdx.x * 256 + t;
    if (a >= ANCH) return;
    float x1, y1, x2, y2;
    anchor_box(a, x1, y1, x2, y2);
    bool inside = (x1 >= 0.f) && (y1 >= 0.f) && (x2 < imv[1]) && (y2 < imv[0]);
    float aa = (x2 - x1) * (y2 - y1);
    float* op = iou_out + (b * ANCH + a) * NG;
    float mx = 0.f;
    for (int g = 0; g < NG; g++) {
        float gx1 = g4[g * 4], gy1 = g4[g * 4 + 1], gx2 = g4[g * 4 + 2], gy2 = g4[g * 4 + 3];
        float l = fmaxf(x1, gx1), r = fminf(x2, gx2);
        float tp = fmaxf(y1, gy1), bo = fminf(y2, gy2);
        float v = 0.f;
        if (l < r && tp < bo) {
            float inter = (r - l) * (bo - tp);
            float ag = (gx2 - gx1) * (gy2 - gy1);
            v = inter / (aa + ag - inter);
        }
        if (!inside) v = 0.f;
        op[g] = v;
        mx = fmaxf(mx, v);
    }
    float lv = (a == idxs) ? 1.f : 0.f;
    if (inside && mx > 0.7f) lv = 0.f;
    lab[b * ANCH + a] = lv;
}

extern "C" void kernel_launch(void* const* d_in, const int* in_sizes, int n_in,
                              void* d_out, int out_size, void* d_ws, size_t ws_size,
                              hipStream_t stream) {
    (void)in_sizes; (void)n_in; (void)out_size; (void)ws_size;
    const float* feats = (const float*)d_in[0];
    const float* w3    = (const float*)d_in[1];
    const float* b3    = (const float*)d_in[2];
    const float* wc    = (const float*)d_in[3];
    const float* bc    = (const float*)d_in[4];
    const float* wb    = (const float*)d_in[5];
    const float* bb    = (const float*)d_in[6];
    const float* gt    = (const float*)d_in[7];
    const float* im    = (const float*)d_in[8];
    float* out = (float*)d_out;
    char* ws = (char*)d_ws;

    // workspace layout (bytes)
    u16* apad = (u16*)(ws);                    // 8*39*52*512 bf16 = 16,613,376 B
    u16* wt   = (u16*)(ws + 16613376);         // 512*4608 bf16    =  4,718,592 B
    u16* whd  = (u16*)(ws + 21331968);         // 64*512 bf16      =     65,536 B
    u16* act  = (u16*)(ws + 21397504);         // 14800*512 bf16   = 15,155,200 B
    float* S  = (float*)(ws + 36552704);       // 14800*64 f32     =  3,788,800 B
    int* idxb = (int*)(ws + 40341504);         // 8 ints

    float* iou_out = out + 799200;
    float* lab     = out + 3463200;

    k_zero<<<dim3(4056), dim3(256), 0, stream>>>((uint4*)apad);
    k_transpose<<<dim3(58, 16, 8), dim3(32, 32), 0, stream>>>(feats, apad);
    k_wt<<<dim3(9216), dim3(256), 0, stream>>>(w3, wt);
    k_whd<<<dim3(128), dim3(256), 0, stream>>>(wc, wb, whd);
    k_conv<<<dim3(116, 4), dim3(256), 0, stream>>>(apad, wt, b3, act);
    k_heads<<<dim3(116), dim3(256), 0, stream>>>(act, whd, S);
    k_final<<<dim3(58), dim3(256), 0, stream>>>(S, bc, bb, out);
    k_idx<<<dim3(1), dim3(64), 0, stream>>>(gt, im, idxb);
    k_iou<<<dim3(66, 8), dim3(256), 0, stream>>>(gt, im, idxb, iou_out, lab);
}

// Round 2
// 230.995 us; speedup vs baseline: 1.1284x; 1.1284x over previous
//
#include <hip/hip_runtime.h>

typedef unsigned short u16;
typedef unsigned int u32;
typedef float f32x4 __attribute__((ext_vector_type(4)));
typedef short bf16x8 __attribute__((ext_vector_type(8)));

#define NB 8
#define FH 37
#define FW 50
#define FHW 1850
#define MTOT 14800
#define CIN 512
#define KTOT 4608
#define HP 39
#define WP 52
#define ANCH 16650
#define NG 20

// ---------- helpers ----------
__device__ __forceinline__ u16 f2bf(float f) {
    u32 u = __float_as_uint(f);
    u += 0x7fffu + ((u >> 16) & 1u);   // round-to-nearest-even
    return (u16)(u >> 16);
}

__device__ __forceinline__ void gl2lds16(const u16* g, u16* l) {
    __builtin_amdgcn_global_load_lds((const __attribute__((address_space(1))) void*)(g),
                                     (__attribute__((address_space(3))) void*)(l),
                                     16, 0, 0);
}

__device__ __forceinline__ void anchor_box(int a, float& x1, float& y1, float& x2, float& y2) {
    // a = ((x*37 + y)*3 + si)*3 + bi
    int x = a / 333;
    int rem = a - x * 333;
    int y = rem / 9;
    int r2 = rem - y * 9;
    int si = r2 / 3;
    int bi = r2 - si * 3;
    float s = (float)(8 << si);
    float fx = (float)x, fy = (float)y;
    float ax1, ay1, ax2, ay2;
    if (bi == 0)      { float h = s * 0.5f;  ax1 = fx - h; ay1 = fy - h; ax2 = fx + h; ay2 = fy + h; }
    else if (bi == 1) { float q = s * 0.25f; ax1 = fx - s; ay1 = fy - q; ax2 = fx + s; ay2 = fy + q; }
    else              { float q = s * 0.25f; ax1 = fx - q; ay1 = fy - s; ax2 = fx + q; ay2 = fy + s; }
    x1 = ax1 * 16.f; y1 = ay1 * 16.f; x2 = ax2 * 16.f; y2 = ay2 * 16.f;
}

// ---------- fused prep: zero apad | repack w3 | repack head weights ----------
__global__ void k_prep(uint4* __restrict__ apad4, const float* __restrict__ w3,
                       u16* __restrict__ wt, const float* __restrict__ wc,
                       const float* __restrict__ wb, u16* __restrict__ whd) {
    int bx = blockIdx.x;
    int t = threadIdx.x;
    if (bx < 4056) {                       // zero apad: 4056*256 uint4 == 16,613,376 B
        apad4[bx * 256 + t] = make_uint4(0u, 0u, 0u, 0u);
    } else if (bx < 13272) {               // wt: (13272-4056)*256 == 2,359,296
        int i = (bx - 4056) * 256 + t;
        int n = i / KTOT;
        int k = i - n * KTOT;
        int tap = k >> 9;
        int ci = k & 511;
        wt[i] = f2bf(w3[n * KTOT + ci * 9 + tap]);
    } else {                               // whd: 128*256 == 32,768
        int i = (bx - 13272) * 256 + t;
        int n = i >> 9;
        int ci = i & 511;
        float v = 0.f;
        if (n < 18) v = wc[n * 512 + ci];
        else if (n < 54) v = wb[(n - 18) * 512 + ci];
        whd[i] = f2bf(v);
    }
}

// feats (B,512,37,50) f32  ->  apad (B,39,52,512) bf16, interior only
__global__ void k_transpose(const float* __restrict__ feats, u16* __restrict__ apad) {
    __shared__ float tile[32][33];
    int b  = blockIdx.z;
    int hw0 = blockIdx.x * 32;
    int c0  = blockIdx.y * 32;
    int tx = threadIdx.x, ty = threadIdx.y;
    int hw = hw0 + tx;
    if (hw < FHW) tile[ty][tx] = feats[(b * 512 + c0 + ty) * FHW + hw];
    __syncthreads();
    int hw2 = hw0 + ty;
    if (hw2 < FHW) {
        int h = hw2 / FW, w = hw2 - h * FW;
        apad[(((b * HP) + h + 1) * WP + (w + 1)) * 512 + c0 + tx] = f2bf(tile[tx][ty]);
    }
}

// ---------- 3x3 conv as implicit GEMM ----------
// C[m][n] = sum_k A[m][k]*Bt[n][k], M=14800 N=512 K=4608
// BM=128 BN=64 BK=64, grid (116,8)=928 blocks, 4 waves each 64x32.
// LDS rows are 128 B (all start at bank 0) -> XOR swizzle chunk^(row&7) applied
// on the GLOBAL fetch address so global_load_lds stays lane-contiguous.
__global__ __launch_bounds__(256) void k_conv(const u16* __restrict__ apad,
                                              const u16* __restrict__ wt,
                                              const float* __restrict__ b3,
                                              u16* __restrict__ act) {
    __shared__ u16 As[128 * 64];   // 16 KB
    __shared__ u16 Bs[64 * 64];    //  8 KB
    int tid = threadIdx.x;
    int wave = tid >> 6, lane = tid & 63;
    int m0 = blockIdx.x * 128;
    int n0 = blockIdx.y * 64;
    int wr = wave >> 1, wn = wave & 1;
    int lm = lane & 15, lq = lane >> 4;
    int l7 = lm & 7;

    f32x4 acc[4][2] = {};

    int rloc = tid >> 3;                    // 0..31 (row within a 32-row call)
    int cg = (tid & 7) ^ (rloc & 7);        // swizzled global chunk for this LDS slot
    int aBase[4], bBase[2];
    for (int i = 0; i < 4; i++) {
        int m = m0 + i * 32 + rloc; if (m > MTOT - 1) m = MTOT - 1;
        int b = m / FHW; int hw = m - b * FHW;
        int h = hw / FW; int w = hw - h * FW;
        aBase[i] = ((b * HP + h) * WP + w) * 512 + cg * 8;
    }
    for (int j = 0; j < 2; j++)
        bBase[j] = (n0 + j * 32 + rloc) * KTOT + cg * 8;

    u16* aL[4]; u16* bL[2];
    for (int i = 0; i < 4; i++) aL[i] = &As[(i * 32 + wave * 8) * 64];
    for (int j = 0; j < 2; j++) bL[j] = &Bs[(j * 32 + wave * 8) * 64];

    for (int kk = 0; kk < KTOT; kk += 64) {
        int tap = kk >> 9;
        int ci0 = kk & 511;
        int dy = tap / 3, dx = tap - dy * 3;
        int aOfs = (dy * WP + dx) * 512 + ci0;
        gl2lds16(apad + aBase[0] + aOfs, aL[0]);
        gl2lds16(apad + aBase[1] + aOfs, aL[1]);
        gl2lds16(apad + aBase[2] + aOfs, aL[2]);
        gl2lds16(apad + aBase[3] + aOfs, aL[3]);
        gl2lds16(wt + bBase[0] + kk, bL[0]);
        gl2lds16(wt + bBase[1] + kk, bL[1]);
        __syncthreads();
        bf16x8 a[2][4], b[2][2];
        #pragma unroll
        for (int ks = 0; ks < 2; ks++) {
            int slotb = ((ks * 4 + lq) ^ l7) * 8;
            #pragma unroll
            for (int i = 0; i < 4; i++)
                a[ks][i] = *(const bf16x8*)&As[(wr * 64 + i * 16 + lm) * 64 + slotb];
            #pragma unroll
            for (int j = 0; j < 2; j++)
                b[ks][j] = *(const bf16x8*)&Bs[(wn * 32 + j * 16 + lm) * 64 + slotb];
        }
        #pragma unroll
        for (int ks = 0; ks < 2; ks++)
            #pragma unroll
            for (int i = 0; i < 4; i++)
                #pragma unroll
                for (int j = 0; j < 2; j++)
                    acc[i][j] = __builtin_amdgcn_mfma_f32_16x16x32_bf16(a[ks][i], b[ks][j], acc[i][j], 0, 0, 0);
        __syncthreads();
    }

    for (int j = 0; j < 2; j++) {
        int n = n0 + wn * 32 + j * 16 + lm;
        float bias = b3[n];
        for (int i = 0; i < 4; i++) {
            int mb = m0 + wr * 64 + i * 16 + lq * 4;
            for (int r = 0; r < 4; r++) {
                int m = mb + r;
                if (m < MTOT) {
                    float v = acc[i][j][r] + bias;
                    act[m * 512 + n] = f2bf(v > 0.f ? v : 0.f);
                }
            }
        }
    }
}

// ---------- 1x1 head convs: S[m][n] = sum_k act[m][k]*whd[n][k] ----------
// grid 232 blocks of 4 waves; each wave: 16 rows x 64 cols.
__global__ __launch_bounds__(256) void k_heads(const u16* __restrict__ act,
                                               const u16* __restrict__ whd,
                                               float* __restrict__ S) {
    int tid = threadIdx.x;
    int wave = tid >> 6, lane = tid & 63;
    int lm = lane & 15, lq = lane >> 4;
    int m0 = blockIdx.x * 64 + wave * 16;
    int mr = m0 + lm; if (mr > MTOT - 1) mr = MTOT - 1;
    const u16* arow = act + mr * 512;
    f32x4 acc[4] = {};
    for (int kk = 0; kk < 512; kk += 32) {
        bf16x8 a = *(const bf16x8*)&arow[kk + lq * 8];
        #pragma unroll
        for (int j = 0; j < 4; j++) {
            bf16x8 b = *(const bf16x8*)&whd[(j * 16 + lm) * 512 + kk + lq * 8];
            acc[j] = __builtin_amdgcn_mfma_f32_16x16x32_bf16(a, b, acc[j], 0, 0, 0);
        }
    }
    #pragma unroll
    for (int r = 0; r < 4; r++) {
        int m = m0 + lq * 4 + r;
        if (m < MTOT)
            for (int j = 0; j < 4; j++)
                S[m * 64 + j * 16 + lm] = acc[j][r];
    }
}

// ---------- softmax pairs + bbox concat, one channel per blockIdx.y ----------
__global__ void k_final(const float* __restrict__ S, const float* __restrict__ bc,
                        const float* __restrict__ bb, float* __restrict__ out) {
    int m = blockIdx.x * 256 + threadIdx.x;
    if (m >= MTOT) return;
    int c = blockIdx.y;
    int b = m / FHW;
    int hw = m - b * FHW;
    float v;
    if (c < 18) {
        int c0 = c < 9 ? c : c - 9;
        float s0 = S[m * 64 + c0] + bc[c0];
        float s1 = S[m * 64 + c0 + 9] + bc[c0 + 9];
        float mx = fmaxf(s0, s1);
        float e0 = __expf(s0 - mx), e1 = __expf(s1 - mx);
        v = (c < 9 ? e0 : e1) / (e0 + e1);
    } else {
        v = S[m * 64 + c] + bb[c - 18];
    }
    out[(b * 54 + c) * FHW + hw] = v;
}

// ---------- IoU matrix + labels (idx fused, LDS-staged coalesced writes) ----------
__global__ __launch_bounds__(256) void k_iou(const float* __restrict__ gt, const float* __restrict__ im,
                                             float* __restrict__ iou_out, float* __restrict__ lab) {
    __shared__ float g4[NG * 4];
    __shared__ float buf[256 * NG];
    __shared__ float imv[2];
    __shared__ int idxs;
    int t = threadIdx.x;
    int b = blockIdx.y;
    if (t < NG * 4) g4[t] = gt[b * NG * 4 + t];
    if (t < 2) imv[t] = im[t];
    __syncthreads();
    if (t == 0) {
        // idx[b] = argmax_g iou(anchor19, gt[b][g]) (first max, inside-masked)
        float x1, y1, x2, y2;
        anchor_box(19, x1, y1, x2, y2);
        bool inside = (x1 >= 0.f) && (y1 >= 0.f) && (x2 < imv[1]) && (y2 < imv[0]);
        float aa = (x2 - x1) * (y2 - y1);
        float best = -1.f; int bg = 0;
        for (int g = 0; g < NG; g++) {
            float gx1 = g4[g * 4], gy1 = g4[g * 4 + 1], gx2 = g4[g * 4 + 2], gy2 = g4[g * 4 + 3];
            float l = fmaxf(x1, gx1), r = fminf(x2, gx2);
            float tp = fmaxf(y1, gy1), bo = fminf(y2, gy2);
            float v = 0.f;
            if (l < r && tp < bo) {
                float inter = (r - l) * (bo - tp);
                float ag = (gx2 - gx1) * (gy2 - gy1);
                v = inter / (aa + ag - inter);
            }
            if (!inside) v = 0.f;
            if (v > best) { best = v; bg = g; }
        }
        idxs = bg;
    }
    int a0 = blockIdx.x * 256;
    int a = a0 + t;
    float mx = 0.f;
    bool inside = false;
    if (a < ANCH) {
        float x1, y1, x2, y2;
        anchor_box(a, x1, y1, x2, y2);
        inside = (x1 >= 0.f) && (y1 >= 0.f) && (x2 < imv[1]) && (y2 < imv[0]);
        float aa = (x2 - x1) * (y2 - y1);
        for (int g = 0; g < NG; g++) {
            float gx1 = g4[g * 4], gy1 = g4[g * 4 + 1], gx2 = g4[g * 4 + 2], gy2 = g4[g * 4 + 3];
            float l = fmaxf(x1, gx1), r = fminf(x2, gx2);
            float tp = fmaxf(y1, gy1), bo = fminf(y2, gy2);
            float v = 0.f;
            if (l < r && tp < bo) {
                float inter = (r - l) * (bo - tp);
                float ag = (gx2 - gx1) * (gy2 - gy1);
                v = inter / (aa + ag - inter);
            }
            if (!inside) v = 0.f;
            buf[t * NG + g] = v;
            mx = fmaxf(mx, v);
        }
    }
    __syncthreads();
    int rem = ANCH - a0;
    int cnt = (rem < 256 ? rem : 256) * NG;
    float* dst = iou_out + (b * ANCH + a0) * NG;
    for (int i = t; i < cnt; i += 256) dst[i] = buf[i];
    if (a < ANCH) {
        float lv = (a == idxs) ? 1.f : 0.f;
        if (inside && mx > 0.7f) lv = 0.f;
        lab[b * ANCH + a] = lv;
    }
}

extern "C" void kernel_launch(void* const* d_in, const int* in_sizes, int n_in,
                              void* d_out, int out_size, void* d_ws, size_t ws_size,
                              hipStream_t stream) {
    (void)in_sizes; (void)n_in; (void)out_size; (void)ws_size;
    const float* feats = (const float*)d_in[0];
    const float* w3    = (const float*)d_in[1];
    const float* b3    = (const float*)d_in[2];
    const float* wc    = (const float*)d_in[3];
    const float* bc    = (const float*)d_in[4];
    const float* wb    = (const float*)d_in[5];
    const float* bb    = (const float*)d_in[6];
    const float* gt    = (const float*)d_in[7];
    const float* im    = (const float*)d_in[8];
    float* out = (float*)d_out;
    char* ws = (char*)d_ws;

    // workspace layout (bytes)
    u16* apad = (u16*)(ws);                    // 8*39*52*512 bf16 = 16,613,376 B
    u16* wt   = (u16*)(ws + 16613376);         // 512*4608 bf16    =  4,718,592 B
    u16* whd  = (u16*)(ws + 21331968);         // 64*512 bf16      =     65,536 B
    u16* act  = (u16*)(ws + 21397504);         // 14800*512 bf16   = 15,155,200 B
    float* S  = (float*)(ws + 36552704);       // 14800*64 f32     =  3,788,800 B

    float* iou_out = out + 799200;
    float* lab     = out + 3463200;

    k_prep<<<dim3(13400), dim3(256), 0, stream>>>((uint4*)apad, w3, wt, wc, wb, whd);
    k_transpose<<<dim3(58, 16, 8), dim3(32, 32), 0, stream>>>(feats, apad);
    k_conv<<<dim3(116, 8), dim3(256), 0, stream>>>(apad, wt, b3, act);
    k_heads<<<dim3(232), dim3(256), 0, stream>>>(act, whd, S);
    k_final<<<dim3(58, 54), dim3(256), 0, stream>>>(S, bc, bb, out);
    k_iou<<<dim3(66, 8), dim3(256), 0, stream>>>(gt, im, iou_out, lab);
}

// Round 3
// 210.275 us; speedup vs baseline: 1.2395x; 1.0985x over previous
//
#include <hip/hip_runtime.h>

typedef unsigned short u16;
typedef unsigned int u32;
typedef float f32x4 __attribute__((ext_vector_type(4)));
typedef short bf16x8 __attribute__((ext_vector_type(8)));

#define NB 8
#define FH 37
#define FW 50
#define FHW 1850
#define MTOT 14800
#define CIN 512
#define KTOT 4608
#define HP 39
#define WP 52
#define ANCH 16650
#define NG 20

// block ranges inside k_pre
#define ZB 356            // pad-ring zero: 356*256 = 91136 uint4
#define WTB 9216          // w3 repack
#define WHB 128           // head-weight repack
#define TRB 7424          // NHWC transpose: 58 x 16 x 8 tiles
#define IOB 528           // iou: 66 x 8
#define PRE_TOT (ZB + WTB + WHB + TRB + IOB)

// ---------- helpers ----------
__device__ __forceinline__ u16 f2bf(float f) {
    u32 u = __float_as_uint(f);
    u += 0x7fffu + ((u >> 16) & 1u);   // round-to-nearest-even
    return (u16)(u >> 16);
}

__device__ __forceinline__ void gl2lds16(const u16* g, u16* l) {
    __builtin_amdgcn_global_load_lds((const __attribute__((address_space(1))) void*)(g),
                                     (__attribute__((address_space(3))) void*)(l),
                                     16, 0, 0);
}

__device__ __forceinline__ void anchor_box(int a, float& x1, float& y1, float& x2, float& y2) {
    // a = ((x*37 + y)*3 + si)*3 + bi
    int x = a / 333;
    int rem = a - x * 333;
    int y = rem / 9;
    int r2 = rem - y * 9;
    int si = r2 / 3;
    int bi = r2 - si * 3;
    float s = (float)(8 << si);
    float fx = (float)x, fy = (float)y;
    float ax1, ay1, ax2, ay2;
    if (bi == 0)      { float h = s * 0.5f;  ax1 = fx - h; ay1 = fy - h; ax2 = fx + h; ay2 = fy + h; }
    else if (bi == 1) { float q = s * 0.25f; ax1 = fx - s; ay1 = fy - q; ax2 = fx + s; ay2 = fy + q; }
    else              { float q = s * 0.25f; ax1 = fx - q; ay1 = fy - s; ax2 = fx + q; ay2 = fy + s; }
    x1 = ax1 * 16.f; y1 = ay1 * 16.f; x2 = ax2 * 16.f; y2 = ay2 * 16.f;
}

// ---------- fused pre-conv + independent work ----------
__global__ __launch_bounds__(256) void k_pre(u16* __restrict__ apad,
                                             const float* __restrict__ w3, u16* __restrict__ wt,
                                             const float* __restrict__ wc, const float* __restrict__ wb,
                                             u16* __restrict__ whd,
                                             const float* __restrict__ feats,
                                             const float* __restrict__ gt, const float* __restrict__ im,
                                             float* __restrict__ iou_out, float* __restrict__ lab) {
    __shared__ __attribute__((aligned(16))) char smraw[20864];
    __shared__ int idxs;
    int blk = blockIdx.x;
    int t = threadIdx.x;

    if (blk < ZB) {
        // zero only the 1-px pad ring (interior gets overwritten by transpose)
        uint4* apad4 = (uint4*)apad;
        int i = blk * 256 + t;               // < 91136
        int img = i / 11392;
        int r = i - img * 11392;
        int u4;
        if (r < 3328) u4 = r;                                   // row 0
        else if (r < 6656) u4 = 126464 + (r - 3328);            // row 38 (38*3328)
        else {
            int rp = r - 6656;                                  // < 4736
            int h = 1 + (rp >> 7);                              // rows 1..37, 128 u4 each
            int c2 = rp & 127;
            int col = (c2 & 64) ? 51 : 0;
            u4 = (h * 52 + col) * 64 + (c2 & 63);
        }
        apad4[img * 129792 + u4] = make_uint4(0u, 0u, 0u, 0u);
    } else if (blk < ZB + WTB) {
        // w3 (512,512,3,3) -> wt[n][tap*512+ci] bf16
        int i = (blk - ZB) * 256 + t;
        int n = i / KTOT;
        int k = i - n * KTOT;
        int tap = k >> 9;
        int ci = k & 511;
        wt[i] = f2bf(w3[n * KTOT + ci * 9 + tap]);
    } else if (blk < ZB + WTB + WHB) {
        int i = (blk - ZB - WTB) * 256 + t;
        int n = i >> 9;
        int ci = i & 511;
        float v = 0.f;
        if (n < 18) v = wc[n * 512 + ci];
        else if (n < 54) v = wb[(n - 18) * 512 + ci];
        whd[i] = f2bf(v);
    } else if (blk < ZB + WTB + WHB + TRB) {
        // feats (B,512,37,50) f32 -> apad (B,39,52,512) bf16 interior
        float* tile = (float*)smraw;         // 32x33 floats
        int q = blk - ZB - WTB - WHB;
        int xt = q % 58;
        int r2 = q / 58;
        int ct = r2 & 15;
        int img = r2 >> 4;
        int hw0 = xt * 32, c0 = ct * 32;
        int tx = t & 31, ty4 = t >> 5;       // ty4 0..7
        #pragma unroll
        for (int rr = 0; rr < 4; rr++) {
            int ty = ty4 + rr * 8;
            int hw = hw0 + tx;
            if (hw < FHW) tile[ty * 33 + tx] = feats[(img * 512 + c0 + ty) * FHW + hw];
        }
        __syncthreads();
        #pragma unroll
        for (int rr = 0; rr < 4; rr++) {
            int ty = ty4 + rr * 8;
            int hw2 = hw0 + ty;
            if (hw2 < FHW) {
                int h = hw2 / FW, w = hw2 - h * FW;
                apad[(((img * HP) + h + 1) * WP + (w + 1)) * 512 + c0 + tx] = f2bf(tile[tx * 33 + ty]);
            }
        }
    } else {
        // IoU matrix + labels (idx fused)
        float* g4 = (float*)smraw;           // 80 floats
        float* imv = g4 + 80;                // 2 floats
        float* buf = g4 + 84;                // 256*20 floats
        int q = blk - ZB - WTB - WHB - TRB;
        int at = q % 66;
        int b = q / 66;
        if (t < NG * 4) g4[t] = gt[b * NG * 4 + t];
        if (t < 2) imv[t] = im[t];
        __syncthreads();
        if (t == 0) {
            float x1, y1, x2, y2;
            anchor_box(19, x1, y1, x2, y2);
            bool inside = (x1 >= 0.f) && (y1 >= 0.f) && (x2 < imv[1]) && (y2 < imv[0]);
            float aa = (x2 - x1) * (y2 - y1);
            float best = -1.f; int bg = 0;
            for (int g = 0; g < NG; g++) {
                float gx1 = g4[g * 4], gy1 = g4[g * 4 + 1], gx2 = g4[g * 4 + 2], gy2 = g4[g * 4 + 3];
                float l = fmaxf(x1, gx1), r = fminf(x2, gx2);
                float tp = fmaxf(y1, gy1), bo = fminf(y2, gy2);
                float v = 0.f;
                if (l < r && tp < bo) {
                    float inter = (r - l) * (bo - tp);
                    float ag = (gx2 - gx1) * (gy2 - gy1);
                    v = inter / (aa + ag - inter);
                }
                if (!inside) v = 0.f;
                if (v > best) { best = v; bg = g; }
            }
            idxs = bg;
        }
        int a0 = at * 256;
        int a = a0 + t;
        float mx = 0.f;
        bool inside = false;
        if (a < ANCH) {
            float x1, y1, x2, y2;
            anchor_box(a, x1, y1, x2, y2);
            inside = (x1 >= 0.f) && (y1 >= 0.f) && (x2 < imv[1]) && (y2 < imv[0]);
            float aa = (x2 - x1) * (y2 - y1);
            for (int g = 0; g < NG; g++) {
                float gx1 = g4[g * 4], gy1 = g4[g * 4 + 1], gx2 = g4[g * 4 + 2], gy2 = g4[g * 4 + 3];
                float l = fmaxf(x1, gx1), r = fminf(x2, gx2);
                float tp = fmaxf(y1, gy1), bo = fminf(y2, gy2);
                float v = 0.f;
                if (l < r && tp < bo) {
                    float inter = (r - l) * (bo - tp);
                    float ag = (gx2 - gx1) * (gy2 - gy1);
                    v = inter / (aa + ag - inter);
                }
                if (!inside) v = 0.f;
                buf[t * NG + g] = v;
                mx = fmaxf(mx, v);
            }
        }
        __syncthreads();
        int rem = ANCH - a0;
        int cnt = (rem < 256 ? rem : 256) * NG;
        float* dst = iou_out + (b * ANCH + a0) * NG;
        for (int i = t; i < cnt; i += 256) dst[i] = buf[i];
        if (a < ANCH) {
            float lv = (a == idxs) ? 1.f : 0.f;
            if (inside && mx > 0.7f) lv = 0.f;
            lab[b * ANCH + a] = lv;
        }
    }
}

// ---------- 3x3 conv as implicit GEMM ----------
// BM=128 BN=64 BK=64, 960 1-D blocks with XCD swizzle: all 8 n-blocks of an
// A-tile row share L%8 (one XCD) so the A-tile stays in that XCD's L2.
__global__ __launch_bounds__(256) void k_conv(const u16* __restrict__ apad,
                                              const u16* __restrict__ wt,
                                              const float* __restrict__ b3,
                                              u16* __restrict__ act) {
    __shared__ u16 As[128 * 64];   // 16 KB
    __shared__ u16 Bs[64 * 64];    //  8 KB
    int L = blockIdx.x;
    int mb = (L & 7) + 8 * (L >> 6);
    int nb = (L >> 3) & 7;
    if (mb >= 116) return;
    int tid = threadIdx.x;
    int wave = tid >> 6, lane = tid & 63;
    int m0 = mb * 128;
    int n0 = nb * 64;
    int wr = wave >> 1, wn = wave & 1;
    int lm = lane & 15, lq = lane >> 4;
    int l7 = lm & 7;

    f32x4 acc[4][2] = {};

    int rloc = tid >> 3;                    // 0..31
    int cg = (tid & 7) ^ (rloc & 7);        // swizzled global chunk
    int aBase[4], bBase[2];
    for (int i = 0; i < 4; i++) {
        int m = m0 + i * 32 + rloc; if (m > MTOT - 1) m = MTOT - 1;
        int b = m / FHW; int hw = m - b * FHW;
        int h = hw / FW; int w = hw - h * FW;
        aBase[i] = ((b * HP + h) * WP + w) * 512 + cg * 8;
    }
    for (int j = 0; j < 2; j++)
        bBase[j] = (n0 + j * 32 + rloc) * KTOT + cg * 8;

    u16* aL[4]; u16* bL[2];
    for (int i = 0; i < 4; i++) aL[i] = &As[(i * 32 + wave * 8) * 64];
    for (int j = 0; j < 2; j++) bL[j] = &Bs[(j * 32 + wave * 8) * 64];

    for (int kk = 0; kk < KTOT; kk += 64) {
        int tap = kk >> 9;
        int ci0 = kk & 511;
        int dy = tap / 3, dx = tap - dy * 3;
        int aOfs = (dy * WP + dx) * 512 + ci0;
        gl2lds16(apad + aBase[0] + aOfs, aL[0]);
        gl2lds16(apad + aBase[1] + aOfs, aL[1]);
        gl2lds16(apad + aBase[2] + aOfs, aL[2]);
        gl2lds16(apad + aBase[3] + aOfs, aL[3]);
        gl2lds16(wt + bBase[0] + kk, bL[0]);
        gl2lds16(wt + bBase[1] + kk, bL[1]);
        __syncthreads();
        bf16x8 a[2][4], b[2][2];
        #pragma unroll
        for (int ks = 0; ks < 2; ks++) {
            int slotb = ((ks * 4 + lq) ^ l7) * 8;
            #pragma unroll
            for (int i = 0; i < 4; i++)
                a[ks][i] = *(const bf16x8*)&As[(wr * 64 + i * 16 + lm) * 64 + slotb];
            #pragma unroll
            for (int j = 0; j < 2; j++)
                b[ks][j] = *(const bf16x8*)&Bs[(wn * 32 + j * 16 + lm) * 64 + slotb];
        }
        #pragma unroll
        for (int ks = 0; ks < 2; ks++)
            #pragma unroll
            for (int i = 0; i < 4; i++)
                #pragma unroll
                for (int j = 0; j < 2; j++)
                    acc[i][j] = __builtin_amdgcn_mfma_f32_16x16x32_bf16(a[ks][i], b[ks][j], acc[i][j], 0, 0, 0);
        __syncthreads();
    }

    for (int j = 0; j < 2; j++) {
        int n = n0 + wn * 32 + j * 16 + lm;
        float bias = b3[n];
        for (int i = 0; i < 4; i++) {
            int mb2 = m0 + wr * 64 + i * 16 + lq * 4;
            for (int r = 0; r < 4; r++) {
                int m = mb2 + r;
                if (m < MTOT) {
                    float v = acc[i][j][r] + bias;
                    act[m * 512 + n] = f2bf(v > 0.f ? v : 0.f);
                }
            }
        }
    }
}

// ---------- fused 1x1 heads + softmax/bias + concat write ----------
// 232 blocks x 4 waves; each wave: 16 rows x 64 cols GEMM -> LDS -> epilogue.
__global__ __launch_bounds__(256) void k_post(const u16* __restrict__ act,
                                              const u16* __restrict__ whd,
                                              const float* __restrict__ bc,
                                              const float* __restrict__ bb,
                                              float* __restrict__ out) {
    __shared__ float Sl[4 * 16 * 65];
    int tid = threadIdx.x;
    int wave = tid >> 6, lane = tid & 63;
    int lm = lane & 15, lq = lane >> 4;
    int m0 = blockIdx.x * 64 + wave * 16;
    int mr = m0 + lm; if (mr > MTOT - 1) mr = MTOT - 1;
    const u16* arow = act + mr * 512;
    f32x4 acc[4] = {};
    for (int kk = 0; kk < 512; kk += 32) {
        bf16x8 a = *(const bf16x8*)&arow[kk + lq * 8];
        #pragma unroll
        for (int j = 0; j < 4; j++) {
            bf16x8 b = *(const bf16x8*)&whd[(j * 16 + lm) * 512 + kk + lq * 8];
            acc[j] = __builtin_amdgcn_mfma_f32_16x16x32_bf16(a, b, acc[j], 0, 0, 0);
        }
    }
    float* S = &Sl[wave * 1040];
    #pragma unroll
    for (int r = 0; r < 4; r++)
        #pragma unroll
        for (int j = 0; j < 4; j++)
            S[(lq * 4 + r) * 65 + j * 16 + lm] = acc[j][r];
    __syncthreads();
    int r16 = lane & 15, cg = lane >> 4;
    int m = m0 + r16;
    if (m < MTOT) {
        int b = m / FHW, hw = m - b * FHW;
        const float* Sr = &S[r16 * 65];
        #pragma unroll
        for (int k = 0; k < 14; k++) {
            int c = cg + 4 * k;
            if (c >= 54) break;
            float v;
            if (c < 18) {
                int c0 = c < 9 ? c : c - 9;
                float s0 = Sr[c0] + bc[c0];
                float s1 = Sr[c0 + 9] + bc[c0 + 9];
                float mx = fmaxf(s0, s1);
                float e0 = __expf(s0 - mx), e1 = __expf(s1 - mx);
                v = (c < 9 ? e0 : e1) / (e0 + e1);
            } else {
                v = Sr[c] + bb[c - 18];
            }
            out[(b * 54 + c) * FHW + hw] = v;
        }
    }
}

extern "C" void kernel_launch(void* const* d_in, const int* in_sizes, int n_in,
                              void* d_out, int out_size, void* d_ws, size_t ws_size,
                              hipStream_t stream) {
    (void)in_sizes; (void)n_in; (void)out_size; (void)ws_size;
    const float* feats = (const float*)d_in[0];
    const float* w3    = (const float*)d_in[1];
    const float* b3    = (const float*)d_in[2];
    const float* wc    = (const float*)d_in[3];
    const float* bc    = (const float*)d_in[4];
    const float* wb    = (const float*)d_in[5];
    const float* bb    = (const float*)d_in[6];
    const float* gt    = (const float*)d_in[7];
    const float* im    = (const float*)d_in[8];
    float* out = (float*)d_out;
    char* ws = (char*)d_ws;

    // workspace layout (bytes)
    u16* apad = (u16*)(ws);                    // 8*39*52*512 bf16 = 16,613,376 B
    u16* wt   = (u16*)(ws + 16613376);         // 512*4608 bf16    =  4,718,592 B
    u16* whd  = (u16*)(ws + 21331968);         // 64*512 bf16      =     65,536 B
    u16* act  = (u16*)(ws + 21397504);         // 14800*512 bf16   = 15,155,200 B

    float* iou_out = out + 799200;
    float* lab     = out + 3463200;

    k_pre<<<dim3(PRE_TOT), dim3(256), 0, stream>>>(apad, w3, wt, wc, wb, whd,
                                                   feats, gt, im, iou_out, lab);
    k_conv<<<dim3(960), dim3(256), 0, stream>>>(apad, wt, b3, act);
    k_post<<<dim3(232), dim3(256), 0, stream>>>(act, whd, bc, bb, out);
}

// Round 4
// 206.799 us; speedup vs baseline: 1.2604x; 1.0168x over previous
//
#include <hip/hip_runtime.h>

typedef unsigned short u16;
typedef unsigned int u32;
typedef float f32x4 __attribute__((ext_vector_type(4)));
typedef short bf16x8 __attribute__((ext_vector_type(8)));

#define NB 8
#define FH 37
#define FW 50
#define FHW 1850
#define MTOT 14800
#define CIN 512
#define KTOT 4608
#define HP 39
#define WP 52
#define ANCH 16650
#define NG 20
#define MPAD 14848
#define PSTRIDE 7602176   // MPAD*512 floats per K-half partial

// k_pre block ranges
#define ZB 356            // pad-ring zero
#define WTB 512           // w3 repack (LDS transpose, 1 block per n)
#define WHB 128           // head-weight repack
#define TRB 7424          // NHWC transpose
#define PRE_TOT (ZB + WTB + WHB + TRB)

// k_conv block ranges
#define CONVB 1856        // 232 (mb,kh) pairs x 8 nb
#define IOB 528           // 66 x 8 iou blocks ride along to fill the tail

// ---------- helpers ----------
__device__ __forceinline__ u16 f2bf(float f) {
    u32 u = __float_as_uint(f);
    u += 0x7fffu + ((u >> 16) & 1u);   // round-to-nearest-even
    return (u16)(u >> 16);
}

__device__ __forceinline__ void gl2lds16(const u16* g, u16* l) {
    __builtin_amdgcn_global_load_lds((const __attribute__((address_space(1))) void*)(g),
                                     (__attribute__((address_space(3))) void*)(l),
                                     16, 0, 0);
}

__device__ __forceinline__ void anchor_box(int a, float& x1, float& y1, float& x2, float& y2) {
    int x = a / 333;
    int rem = a - x * 333;
    int y = rem / 9;
    int r2 = rem - y * 9;
    int si = r2 / 3;
    int bi = r2 - si * 3;
    float s = (float)(8 << si);
    float fx = (float)x, fy = (float)y;
    float ax1, ay1, ax2, ay2;
    if (bi == 0)      { float h = s * 0.5f;  ax1 = fx - h; ay1 = fy - h; ax2 = fx + h; ay2 = fy + h; }
    else if (bi == 1) { float q = s * 0.25f; ax1 = fx - s; ay1 = fy - q; ax2 = fx + s; ay2 = fy + q; }
    else              { float q = s * 0.25f; ax1 = fx - q; ay1 = fy - s; ax2 = fx + q; ay2 = fy + s; }
    x1 = ax1 * 16.f; y1 = ay1 * 16.f; x2 = ax2 * 16.f; y2 = ay2 * 16.f;
}

// ---------- fused prep ----------
__global__ __launch_bounds__(256) void k_pre(u16* __restrict__ apad,
                                             const float* __restrict__ w3, u16* __restrict__ wt,
                                             const float* __restrict__ wc, const float* __restrict__ wb,
                                             u16* __restrict__ whd,
                                             const float* __restrict__ feats) {
    __shared__ __attribute__((aligned(16))) char smraw[18432];
    int blk = blockIdx.x;
    int t = threadIdx.x;

    if (blk < ZB) {
        // zero only the 1-px pad ring (interior overwritten by transpose)
        uint4* apad4 = (uint4*)apad;
        int i = blk * 256 + t;               // < 91136
        int img = i / 11392;
        int r = i - img * 11392;
        int u4;
        if (r < 3328) u4 = r;                                   // row 0
        else if (r < 6656) u4 = 126464 + (r - 3328);            // row 38
        else {
            int rp = r - 6656;
            int h = 1 + (rp >> 7);
            int c2 = rp & 127;
            int col = (c2 & 64) ? 51 : 0;
            u4 = (h * 52 + col) * 64 + (c2 & 63);
        }
        apad4[img * 129792 + u4] = make_uint4(0u, 0u, 0u, 0u);
    } else if (blk < ZB + WTB) {
        // w3[n] (512,3,3) -> wt[n][tap*512+ci], coalesced via LDS transpose
        float* lt = (float*)smraw;           // 4608 floats
        int n = blk - ZB;
        const float* src = w3 + n * KTOT;
        for (int i = t; i < KTOT; i += 256) lt[i] = src[i];
        __syncthreads();
        u16* dst = wt + n * KTOT;
        for (int o = t; o < KTOT; o += 256) {
            int tap = o >> 9, ci = o & 511;
            dst[o] = f2bf(lt[ci * 9 + tap]);
        }
    } else if (blk < ZB + WTB + WHB) {
        int i = (blk - ZB - WTB) * 256 + t;
        int n = i >> 9;
        int ci = i & 511;
        float v = 0.f;
        if (n < 18) v = wc[n * 512 + ci];
        else if (n < 54) v = wb[(n - 18) * 512 + ci];
        whd[i] = f2bf(v);
    } else {
        // feats (B,512,37,50) f32 -> apad (B,39,52,512) bf16 interior
        float* tile = (float*)smraw;         // 32x33 floats
        int q = blk - ZB - WTB - WHB;
        int xt = q % 58;
        int r2 = q / 58;
        int ct = r2 & 15;
        int img = r2 >> 4;
        int hw0 = xt * 32, c0 = ct * 32;
        int tx = t & 31, ty4 = t >> 5;
        #pragma unroll
        for (int rr = 0; rr < 4; rr++) {
            int ty = ty4 + rr * 8;
            int hw = hw0 + tx;
            if (hw < FHW) tile[ty * 33 + tx] = feats[(img * 512 + c0 + ty) * FHW + hw];
        }
        __syncthreads();
        #pragma unroll
        for (int rr = 0; rr < 4; rr++) {
            int ty = ty4 + rr * 8;
            int hw2 = hw0 + ty;
            if (hw2 < FHW) {
                int h = hw2 / FW, w = hw2 - h * FW;
                apad[(((img * HP) + h + 1) * WP + (w + 1)) * 512 + c0 + tx] = f2bf(tile[tx * 33 + ty]);
            }
        }
    }
}

// ---------- 3x3 conv as implicit GEMM, split-K=2, + IoU tail blocks ----------
// Conv: BM=128 BN=64 BK=64, K-half 2304 per block. 232 (mb,kh) pairs x 8 nb.
// XCD decode: all 8 nb of one (mb,kh) share L%8 (one XCD) for A-tile L2 reuse.
__global__ __launch_bounds__(256) void k_conv(const u16* __restrict__ apad,
                                              const u16* __restrict__ wt,
                                              float* __restrict__ P,
                                              const float* __restrict__ gt,
                                              const float* __restrict__ im,
                                              float* __restrict__ iou_out,
                                              float* __restrict__ lab) {
    __shared__ __attribute__((aligned(16))) char sm[24576];
    __shared__ int idxs;
    int L = blockIdx.x;
    int tid = threadIdx.x;

    if (L < CONVB) {
        u16* As = (u16*)sm;                 // 128x64 bf16, 16 KB
        u16* Bs = (u16*)(sm + 16384);       // 64x64 bf16, 8 KB
        int g = L >> 6;
        int pair = (L & 7) + 8 * g;         // 0..231
        int nb = (L >> 3) & 7;
        int mb = pair >> 1;
        int kh = pair & 1;
        int wave = tid >> 6, lane = tid & 63;
        int m0 = mb * 128;
        int n0 = nb * 64;
        int wr = wave >> 1, wn = wave & 1;
        int lm = lane & 15, lq = lane >> 4;
        int l7 = lm & 7;

        f32x4 acc[4][2] = {};

        int rloc = tid >> 3;
        int cg = (tid & 7) ^ (rloc & 7);
        int aBase[4], bBase[2];
        for (int i = 0; i < 4; i++) {
            int m = m0 + i * 32 + rloc; if (m > MTOT - 1) m = MTOT - 1;
            int b = m / FHW; int hw = m - b * FHW;
            int h = hw / FW; int w = hw - h * FW;
            aBase[i] = ((b * HP + h) * WP + w) * 512 + cg * 8;
        }
        for (int j = 0; j < 2; j++)
            bBase[j] = (n0 + j * 32 + rloc) * KTOT + cg * 8;

        u16* aL[4]; u16* bL[2];
        for (int i = 0; i < 4; i++) aL[i] = &As[(i * 32 + wave * 8) * 64];
        for (int j = 0; j < 2; j++) bL[j] = &Bs[(j * 32 + wave * 8) * 64];

        int kEnd = (kh + 1) * 2304;
        for (int kk = kh * 2304; kk < kEnd; kk += 64) {
            int tap = kk >> 9;
            int ci0 = kk & 511;
            int dy = tap / 3, dx = tap - dy * 3;
            int aOfs = (dy * WP + dx) * 512 + ci0;
            gl2lds16(apad + aBase[0] + aOfs, aL[0]);
            gl2lds16(apad + aBase[1] + aOfs, aL[1]);
            gl2lds16(apad + aBase[2] + aOfs, aL[2]);
            gl2lds16(apad + aBase[3] + aOfs, aL[3]);
            gl2lds16(wt + bBase[0] + kk, bL[0]);
            gl2lds16(wt + bBase[1] + kk, bL[1]);
            __syncthreads();
            bf16x8 a[2][4], b[2][2];
            #pragma unroll
            for (int ks = 0; ks < 2; ks++) {
                int slotb = ((ks * 4 + lq) ^ l7) * 8;
                #pragma unroll
                for (int i = 0; i < 4; i++)
                    a[ks][i] = *(const bf16x8*)&As[(wr * 64 + i * 16 + lm) * 64 + slotb];
                #pragma unroll
                for (int j = 0; j < 2; j++)
                    b[ks][j] = *(const bf16x8*)&Bs[(wn * 32 + j * 16 + lm) * 64 + slotb];
            }
            #pragma unroll
            for (int ks = 0; ks < 2; ks++)
                #pragma unroll
                for (int i = 0; i < 4; i++)
                    #pragma unroll
                    for (int j = 0; j < 2; j++)
                        acc[i][j] = __builtin_amdgcn_mfma_f32_16x16x32_bf16(a[ks][i], b[ks][j], acc[i][j], 0, 0, 0);
            __syncthreads();
        }

        float* Pp = P + (size_t)kh * PSTRIDE;
        for (int j = 0; j < 2; j++) {
            int n = n0 + wn * 32 + j * 16 + lm;
            for (int i = 0; i < 4; i++) {
                int mb2 = m0 + wr * 64 + i * 16 + lq * 4;
                for (int r = 0; r < 4; r++) {
                    int m = mb2 + r;
                    if (m < MTOT) Pp[m * 512 + n] = acc[i][j][r];
                }
            }
        }
    } else {
        // IoU matrix + labels (idx fused)
        float* g4 = (float*)sm;              // 80 floats
        float* imv = g4 + 80;                // 2
        float* buf = g4 + 84;                // 256*20
        int q = L - CONVB;
        int at = q % 66;
        int b = q / 66;
        int t = tid;
        if (t < NG * 4) g4[t] = gt[b * NG * 4 + t];
        if (t < 2) imv[t] = im[t];
        __syncthreads();
        if (t == 0) {
            float x1, y1, x2, y2;
            anchor_box(19, x1, y1, x2, y2);
            bool inside = (x1 >= 0.f) && (y1 >= 0.f) && (x2 < imv[1]) && (y2 < imv[0]);
            float aa = (x2 - x1) * (y2 - y1);
            float best = -1.f; int bg = 0;
            for (int g2 = 0; g2 < NG; g2++) {
                float gx1 = g4[g2 * 4], gy1 = g4[g2 * 4 + 1], gx2 = g4[g2 * 4 + 2], gy2 = g4[g2 * 4 + 3];
                float l = fmaxf(x1, gx1), r = fminf(x2, gx2);
                float tp = fmaxf(y1, gy1), bo = fminf(y2, gy2);
                float v = 0.f;
                if (l < r && tp < bo) {
                    float inter = (r - l) * (bo - tp);
                    float ag = (gx2 - gx1) * (gy2 - gy1);
                    v = inter / (aa + ag - inter);
                }
                if (!inside) v = 0.f;
                if (v > best) { best = v; bg = g2; }
            }
            idxs = bg;
        }
        int a0 = at * 256;
        int a = a0 + t;
        float mx = 0.f;
        bool inside = false;
        if (a < ANCH) {
            float x1, y1, x2, y2;
            anchor_box(a, x1, y1, x2, y2);
            inside = (x1 >= 0.f) && (y1 >= 0.f) && (x2 < imv[1]) && (y2 < imv[0]);
            float aa = (x2 - x1) * (y2 - y1);
            for (int g2 = 0; g2 < NG; g2++) {
                float gx1 = g4[g2 * 4], gy1 = g4[g2 * 4 + 1], gx2 = g4[g2 * 4 + 2], gy2 = g4[g2 * 4 + 3];
                float l = fmaxf(x1, gx1), r = fminf(x2, gx2);
                float tp = fmaxf(y1, gy1), bo = fminf(y2, gy2);
                float v = 0.f;
                if (l < r && tp < bo) {
                    float inter = (r - l) * (bo - tp);
                    float ag = (gx2 - gx1) * (gy2 - gy1);
                    v = inter / (aa + ag - inter);
                }
                if (!inside) v = 0.f;
                buf[t * NG + g2] = v;
                mx = fmaxf(mx, v);
            }
        }
        __syncthreads();
        int rem = ANCH - a0;
        int cnt = (rem < 256 ? rem : 256) * NG;
        float* dst = iou_out + (b * ANCH + a0) * NG;
        for (int i = t; i < cnt; i += 256) dst[i] = buf[i];
        if (a < ANCH) {
            float lv = (a == idxs) ? 1.f : 0.f;
            if (inside && mx > 0.7f) lv = 0.f;
            lab[b * ANCH + a] = lv;
        }
    }
}

// ---------- reduce + bias/relu/cast + 1x1 heads + softmax + concat write ----------
// 464 blocks x 32 rows. Phase1: act_tile = relu(P0+P1+b3) -> bf16 LDS (XOR-chunk
// layout, conflict-free MFMA reads). Phase2: wave pairs split K=512 into 256+256.
__global__ __launch_bounds__(256) void k_post(const float* __restrict__ P,
                                              const u16* __restrict__ whd,
                                              const float* __restrict__ b3,
                                              const float* __restrict__ bc,
                                              const float* __restrict__ bb,
                                              float* __restrict__ out) {
    __shared__ __attribute__((aligned(16))) u16 actT[32 * 64 * 8];   // 32 KB
    __shared__ float Sl[4][16][68];
    int t = threadIdx.x;
    int m0 = blockIdx.x * 32;
    const float* P0 = P;
    const float* P1 = P + PSTRIDE;

    // phase 1: reduce partials, bias, relu, cast, store swizzled
    #pragma unroll
    for (int i = 0; i < 16; i++) {
        int idx = t + i * 256;               // 0..4095
        int row = idx >> 7, col4 = idx & 127;
        size_t off = (size_t)(m0 + row) * 512 + col4 * 4;
        f32x4 p0 = *(const f32x4*)&P0[off];
        f32x4 p1 = *(const f32x4*)&P1[off];
        f32x4 bi = *(const f32x4*)&b3[col4 * 4];
        u32 lo, hi;
        {
            float v0 = p0[0] + p1[0] + bi[0]; v0 = v0 > 0.f ? v0 : 0.f;
            float v1 = p0[1] + p1[1] + bi[1]; v1 = v1 > 0.f ? v1 : 0.f;
            float v2 = p0[2] + p1[2] + bi[2]; v2 = v2 > 0.f ? v2 : 0.f;
            float v3 = p0[3] + p1[3] + bi[3]; v3 = v3 > 0.f ? v3 : 0.f;
            lo = (u32)f2bf(v0) | ((u32)f2bf(v1) << 16);
            hi = (u32)f2bf(v2) | ((u32)f2bf(v3) << 16);
        }
        int slot = row * 64 + ((col4 >> 1) ^ (row & 7));
        *(uint2*)&actT[slot * 8 + (col4 & 1) * 4] = make_uint2(lo, hi);
    }
    __syncthreads();

    // phase 2: head GEMM, wave pairs split K
    int wave = t >> 6, lane = t & 63, lm = lane & 15, lq = lane >> 4;
    int g = wave >> 1, kh = wave & 1;
    int rowLoc = g * 16 + lm;
    f32x4 acc[4] = {};
    #pragma unroll
    for (int s = 0; s < 8; s++) {
        int kk = kh * 256 + s * 32;
        int c = (kk >> 3) + lq;
        bf16x8 a = *(const bf16x8*)&actT[(rowLoc * 64 + (c ^ (rowLoc & 7))) * 8];
        #pragma unroll
        for (int j = 0; j < 4; j++) {
            bf16x8 b = *(const bf16x8*)&whd[(j * 16 + lm) * 512 + kk + lq * 8];
            acc[j] = __builtin_amdgcn_mfma_f32_16x16x32_bf16(a, b, acc[j], 0, 0, 0);
        }
    }
    #pragma unroll
    for (int r = 0; r < 4; r++)
        #pragma unroll
        for (int j = 0; j < 4; j++)
            Sl[wave][lq * 4 + r][j * 16 + lm] = acc[j][r];
    __syncthreads();

    // epilogue: sum K-half partials + softmax/bias, coalesced write
    for (int i = t; i < 32 * 54; i += 256) {
        int row = i & 31, cc = i >> 5;
        int m = m0 + row;
        if (m >= MTOT) continue;
        int g2 = (row >> 4) * 2, rl = row & 15;
        float v;
        if (cc < 18) {
            int c0 = cc < 9 ? cc : cc - 9;
            float s0 = Sl[g2][rl][c0] + Sl[g2 + 1][rl][c0] + bc[c0];
            float s1 = Sl[g2][rl][c0 + 9] + Sl[g2 + 1][rl][c0 + 9] + bc[c0 + 9];
            float mx = fmaxf(s0, s1);
            float e0 = __expf(s0 - mx), e1 = __expf(s1 - mx);
            v = (cc < 9 ? e0 : e1) / (e0 + e1);
        } else {
            v = Sl[g2][rl][cc] + Sl[g2 + 1][rl][cc] + bb[cc - 18];
        }
        int b = m / FHW, hw = m - b * FHW;
        out[(b * 54 + cc) * FHW + hw] = v;
    }
}

extern "C" void kernel_launch(void* const* d_in, const int* in_sizes, int n_in,
                              void* d_out, int out_size, void* d_ws, size_t ws_size,
                              hipStream_t stream) {
    (void)in_sizes; (void)n_in; (void)out_size; (void)ws_size;
    const float* feats = (const float*)d_in[0];
    const float* w3    = (const float*)d_in[1];
    const float* b3    = (const float*)d_in[2];
    const float* wc    = (const float*)d_in[3];
    const float* bc    = (const float*)d_in[4];
    const float* wb    = (const float*)d_in[5];
    const float* bb    = (const float*)d_in[6];
    const float* gt    = (const float*)d_in[7];
    const float* im    = (const float*)d_in[8];
    float* out = (float*)d_out;
    char* ws = (char*)d_ws;

    // workspace layout (bytes)
    u16* apad = (u16*)(ws);                    // 8*39*52*512 bf16 = 16,613,376 B
    u16* wt   = (u16*)(ws + 16613376);         // 512*4608 bf16    =  4,718,592 B
    u16* whd  = (u16*)(ws + 21331968);         // 64*512 bf16      =     65,536 B
    float* P  = (float*)(ws + 21397504);       // 2 x 14848*512 f32 = 60,817,408 B (total 82.2 MB)

    float* iou_out = out + 799200;
    float* lab     = out + 3463200;

    k_pre<<<dim3(PRE_TOT), dim3(256), 0, stream>>>(apad, w3, wt, wc, wb, whd, feats);
    k_conv<<<dim3(CONVB + IOB), dim3(256), 0, stream>>>(apad, wt, P, gt, im, iou_out, lab);
    k_post<<<dim3(464), dim3(256), 0, stream>>>(P, whd, b3, bc, bb, out);
}